// Round 3
// baseline (461.132 us; speedup 1.0000x reference)
//
#include <hip/hip_runtime.h>
#include <stdint.h>

// PRNG ledger: scheme "partitionable, bits = out0 ^ out1" CONFIRMED (round 2: output 0 passed).
#define BLOCK 1024
#define NW (BLOCK / 64)
#define CAP 8192

__device__ __forceinline__ unsigned fkey(float x) {
  unsigned u = __float_as_uint(x);
  return (u & 0x80000000u) ? ~u : (u | 0x80000000u);
}
__device__ __forceinline__ float funkey(unsigned k) {
  return __uint_as_float((k & 0x80000000u) ? (k & 0x7FFFFFFFu) : ~k);
}

__device__ __forceinline__ void threefry(unsigned x0, unsigned x1, unsigned& o0, unsigned& o1) {
  const unsigned ks0 = 0u, ks1 = 42u, ks2 = 0u ^ 42u ^ 0x1BD11BDAu;
  x0 += ks0; x1 += ks1;
#define TF_ROUND(r) { x0 += x1; x1 = (x1 << (r)) | (x1 >> (32 - (r))); x1 ^= x0; }
  TF_ROUND(13) TF_ROUND(15) TF_ROUND(26) TF_ROUND(6)
  x0 += ks1; x1 += ks2 + 1u;
  TF_ROUND(17) TF_ROUND(29) TF_ROUND(16) TF_ROUND(24)
  x0 += ks2; x1 += ks0 + 2u;
  TF_ROUND(13) TF_ROUND(15) TF_ROUND(26) TF_ROUND(6)
  x0 += ks0; x1 += ks1 + 3u;
  TF_ROUND(17) TF_ROUND(29) TF_ROUND(16) TF_ROUND(24)
  x0 += ks1; x1 += ks2 + 4u;
  TF_ROUND(13) TF_ROUND(15) TF_ROUND(26) TF_ROUND(6)
  x0 += ks2; x1 += ks0 + 5u;
#undef TF_ROUND
  o0 = x0; o1 = x1;
}

__device__ __forceinline__ float gumbel_from_bits(unsigned bits) {
  const float tiny = 1.17549435e-38f;
  float f = __uint_as_float((bits >> 9) | 0x3F800000u) - 1.0f;
  float u = fmaxf(tiny, f * (1.0f - tiny) + tiny);
  return -logf(-logf(u));
}

__device__ __forceinline__ float gumbel_noise(unsigned long long j) {
  unsigned o0, o1;
  threefry((unsigned)(j >> 32), (unsigned)j, o0, o1);
  return gumbel_from_bits(o0 ^ o1);
}

// Static-index insertion of key into descending t5[0..4] (no runtime-indexed arrays).
#define T5_INSERT(t5, key) do {                                             \
    if ((key) > (t5)[4]) {                                                  \
      (t5)[4] = (key);                                                      \
      unsigned long long _tmp;                                              \
      if ((t5)[4] > (t5)[3]) { _tmp=(t5)[4]; (t5)[4]=(t5)[3]; (t5)[3]=_tmp; }\
      if ((t5)[3] > (t5)[2]) { _tmp=(t5)[3]; (t5)[3]=(t5)[2]; (t5)[2]=_tmp; }\
      if ((t5)[2] > (t5)[1]) { _tmp=(t5)[2]; (t5)[2]=(t5)[1]; (t5)[1]=_tmp; }\
      if ((t5)[1] > (t5)[0]) { _tmp=(t5)[1]; (t5)[1]=(t5)[0]; (t5)[0]=_tmp; }\
    }                                                                       \
  } while (0)

extern "C" __global__ void __launch_bounds__(BLOCK)
sampler_kernel(const float* __restrict__ logits,
               const float* __restrict__ temperature,
               const int* __restrict__ topk,
               const float* __restrict__ topp,
               float* __restrict__ out, int B, int V)
{
  __shared__ unsigned long long cand[CAP];
  __shared__ float aux[CAP];
  __shared__ float thsum[BLOCK];
  __shared__ float redf[NW];
  __shared__ float redf2[NW];
  __shared__ float redf3[NW];
  __shared__ unsigned long long redu[NW];
  __shared__ unsigned long long t5red[NW][5];
  __shared__ int   sh_n0;
  __shared__ float sh_t0, sh_sigma;
  __shared__ int   sh_pos0, sh_pos1;
  __shared__ float sh_S1, sh_S2;
  __shared__ unsigned long long sh_best;

  const int b = blockIdx.x;
  const int tid = threadIdx.x;
  const int lane = tid & 63;
  const int wid = tid >> 6;
  const float t = temperature[b];
  const int kk = topk[b];
  const float p = topp[b];
  const float* __restrict__ row = logits + (size_t)b * V;

  // ---- Phase 1: row stats (mean, var) for threshold guess ----
  float ls = 0.f, ls2 = 0.f;
  for (int v = tid; v < V; v += BLOCK) {
    float x = row[v] / t;
    ls += x; ls2 += x * x;
  }
#pragma unroll
  for (int o = 32; o; o >>= 1) { ls += __shfl_down(ls, o); ls2 += __shfl_down(ls2, o); }
  if (lane == 0) { redf2[wid] = ls; redf3[wid] = ls2; }
  __syncthreads();
  if (tid == 0) {
    float s = 0.f, s2 = 0.f;
    for (int i = 0; i < NW; i++) { s += redf2[i]; s2 += redf3[i]; }
    float mu = s / (float)V;
    float var = fmaxf(s2 / (float)V - mu * mu, 0.f);
    float sigma = sqrtf(var);
    if (!(sigma > 1e-20f)) sigma = 1.f;
    int target = min(4096, max(2048, 4 * kk));
    float q = (float)target / (float)V;
    float tt = sqrtf(-2.f * logf(q));
    float z = tt - (2.30753f + 0.27061f * tt) / (1.f + 0.99229f * tt + 0.04481f * tt * tt);
    sh_sigma = sigma;
    sh_t0 = mu + sigma * (z - 0.18f);
  }
  __syncthreads();

  // ---- Phase 2: gather candidates x >= t0; FUSED exact top-5 tournament ----
  // Tournament key: (fkey(x) << 32) | (0xFFFFFFFF - idx)  ==> descending key order
  // is exactly lax.top_k order (value desc, ties -> lowest index). Independent of
  // the sort path: immune to any cand[]-ordering defect.
  unsigned long long t5[5] = {0ull, 0ull, 0ull, 0ull, 0ull};
  int n0 = 0;
  for (int attempt = 0; attempt < 8; ++attempt) {
    if (tid == 0) sh_n0 = 0;
    __syncthreads();
    const float thr = sh_t0;
    for (int v = tid; v < V; v += BLOCK) {
      float x = row[v] / t;
      if (attempt == 0) {
        unsigned long long key =
            ((unsigned long long)fkey(x) << 32) | (unsigned)(0xFFFFFFFFu - (unsigned)v);
        T5_INSERT(t5, key);
      }
      bool pred = (x >= thr);
      unsigned long long mk = __ballot(pred);
      int base = 0;
      if (lane == 0 && mk) base = atomicAdd(&sh_n0, __popcll(mk));
      base = __shfl(base, 0);
      if (pred) {
        int pos = base + __popcll(mk & ((1ull << lane) - 1ull));
        if (pos < CAP)
          cand[pos] = ((unsigned long long)fkey(x) << 32) | (unsigned)v;
      }
    }
    __syncthreads();
    n0 = sh_n0;
    if (n0 >= kk && n0 <= CAP) break;
    if (tid == 0) {
      if (n0 < kk) sh_t0 = sh_t0 - 0.6f * sh_sigma;
      else         sh_t0 = sh_t0 + 0.3f * sh_sigma;
    }
    __syncthreads();
  }
  if (n0 > CAP) n0 = CAP;

  // ---- Tournament reduction: wave merge via shfl, then block merge ----
  {
#pragma unroll
    for (int off = 32; off; off >>= 1) {
      unsigned long long o0 = __shfl_down(t5[0], off);
      unsigned long long o1 = __shfl_down(t5[1], off);
      unsigned long long o2 = __shfl_down(t5[2], off);
      unsigned long long o3 = __shfl_down(t5[3], off);
      unsigned long long o4 = __shfl_down(t5[4], off);
      T5_INSERT(t5, o0); T5_INSERT(t5, o1); T5_INSERT(t5, o2);
      T5_INSERT(t5, o3); T5_INSERT(t5, o4);
    }
    if (lane == 0) {
      t5red[wid][0] = t5[0]; t5red[wid][1] = t5[1]; t5red[wid][2] = t5[2];
      t5red[wid][3] = t5[3]; t5red[wid][4] = t5[4];
    }
  }
  __syncthreads();

  if (n0 < 1) {
    if (tid == 0) {
      out[b] = 0.f;
      for (int j = 0; j < 6; j++) { out[B + b * 6 + j] = 0.f; out[B + B * 6 + b * 6 + j] = 0.f; }
    }
    return;
  }

  // ---- Phase 3: bitonic sort candidates ascending by (value_key, idx) ----
  int n = 1; while (n < n0) n <<= 1;
  if (n < 2) n = 2;
  for (int i = n0 + tid; i < n; i += BLOCK) cand[i] = 0xFFFFFFFFFFFFFFFFull;
  __syncthreads();
  for (int sz = 2; sz <= n; sz <<= 1) {
    for (int st = sz >> 1; st > 0; st >>= 1) {
      for (int i = tid; i < n; i += BLOCK) {
        int j = i ^ st;
        if (j > i) {
          unsigned long long a = cand[i], c = cand[j];
          bool up = ((i & sz) == 0);
          if ((a > c) == up) { cand[i] = c; cand[j] = a; }
        }
      }
      __syncthreads();
    }
  }

  const float M = funkey((unsigned)(cand[n0 - 1] >> 32));   // exact row max

  // ---- Phase 4: top-k threshold position (ties kept) ----
  if (tid == 0) {
    int kc = min(kk, n0);
    unsigned tk = (unsigned)(cand[n0 - kc] >> 32);
    int lo = 0, hi = n0 - kc;
    while (lo < hi) { int mid = (lo + hi) >> 1;
      if ((unsigned)(cand[mid] >> 32) >= tk) hi = mid; else lo = mid + 1; }
    sh_pos0 = lo;
  }
  __syncthreads();
  const int pos0 = sh_pos0;

  // ---- q_i = exp(x - M) for kept-by-topk; S1 = sum ----
  for (int i = tid; i < n0; i += BLOCK) {
    float v = funkey((unsigned)(cand[i] >> 32));
    aux[i] = (i >= pos0) ? expf(v - M) : 0.f;
  }
  __syncthreads();
  {
    float sloc = 0.f;
    for (int i = tid; i < n0; i += BLOCK) sloc += aux[i];
#pragma unroll
    for (int o = 32; o; o >>= 1) sloc += __shfl_down(sloc, o);
    if (lane == 0) redf[wid] = sloc;
    __syncthreads();
    if (tid == 0) { float s = 0.f; for (int i = 0; i < NW; i++) s += redf[i]; sh_S1 = s; }
    __syncthreads();
  }
  const float S1 = sh_S1;

  // ---- inclusive cumsum of p_i = q_i/S1 ----
  const int C = (n0 + BLOCK - 1) / BLOCK;
  const int beg = tid * C, endp = min(beg + C, n0);
  float sp = 0.f;
  for (int i = beg; i < endp; i++) sp += aux[i] / S1;
  thsum[tid] = sp;
  __syncthreads();
  for (int off = 1; off < BLOCK; off <<= 1) {
    float vv = (tid >= off) ? thsum[tid - off] : 0.f;
    __syncthreads();
    thsum[tid] += vv;
    __syncthreads();
  }
  {
    float run = (tid > 0) ? thsum[tid - 1] : 0.f;
    for (int i = beg; i < endp; i++) { run += aux[i] / S1; aux[i] = run; }
  }
  __syncthreads();

  // ---- top-p cut: first pos with cum > 1-p ----
  const float cutoff = 1.0f - p;
  if (tid == 0) {
    int lo = pos0, hi = n0 - 1;
    while (lo < hi) { int mid = (lo + hi) >> 1;
      if (aux[mid] > cutoff) hi = mid; else lo = mid + 1; }
    sh_pos1 = lo;
  }
  __syncthreads();
  const int pos1 = sh_pos1;

  // ---- S2 over final kept set ----
  {
    float sloc = 0.f;
    for (int i = pos1 + tid; i < n0; i += BLOCK) {
      float v = funkey((unsigned)(cand[i] >> 32));
      sloc += expf(v - M);
    }
#pragma unroll
    for (int o = 32; o; o >>= 1) sloc += __shfl_down(sloc, o);
    if (lane == 0) redf2[wid] = sloc;
    __syncthreads();
    if (tid == 0) { float s = 0.f; for (int i = 0; i < NW; i++) s += redf2[i]; sh_S2 = s; }
    __syncthreads();
  }

  // ---- Gumbel-max sampling (first-occurrence tie-break via ~i) ----
  unsigned long long best = 0ull;
  for (int i = pos1 + tid; i < n0; i += BLOCK) {
    unsigned idx = (unsigned)(cand[i] & 0xFFFFFFFFull);
    unsigned long long j = (unsigned long long)b * (unsigned long long)V + idx;
    float g = gumbel_noise(j);
    float v = funkey((unsigned)(cand[i] >> 32));
    float sc = v + g;
    unsigned long long pk =
        ((unsigned long long)fkey(sc) << 32) | (unsigned)(0xFFFFFFFFu - (unsigned)i);
    if (pk > best) best = pk;
  }
#pragma unroll
  for (int o = 32; o; o >>= 1) {
    unsigned long long o2 = __shfl_down(best, o);
    if (o2 > best) best = o2;
  }
  if (lane == 0) redu[wid] = best;
  __syncthreads();
  if (tid == 0) {
    unsigned long long bb = 0ull;
    for (int i = 0; i < NW; i++) if (redu[i] > bb) bb = redu[i];
    sh_best = bb;
  }
  __syncthreads();

  // ---- Phase 5: outputs ----
  if (tid == 0) {
    const float lse = logf(sh_S2);
    int bi = (int)(0xFFFFFFFFu - (unsigned)(sh_best & 0xFFFFFFFFull));
    unsigned sidx = (unsigned)(cand[bi] & 0xFFFFFFFFull);
    float sval = funkey((unsigned)(cand[bi] >> 32));

    // Final top-5 from tournament (merge the 16 wave leaders; static indices only).
    unsigned long long f5[5] = {0ull, 0ull, 0ull, 0ull, 0ull};
    for (int w = 0; w < NW; w++) {
      unsigned long long k0 = t5red[w][0], k1 = t5red[w][1], k2 = t5red[w][2],
                         k3 = t5red[w][3], k4 = t5red[w][4];
      T5_INSERT(f5, k0); T5_INSERT(f5, k1); T5_INSERT(f5, k2);
      T5_INSERT(f5, k3); T5_INSERT(f5, k4);
    }

    out[b] = (float)sidx;
    float* lpout = out + B + b * 6;
    float* idout = out + B + B * 6 + b * 6;
    float tv0 = funkey((unsigned)(f5[0] >> 32));
    // f5[0] is the row max; use it for M consistency check-free epilogue
    (void)tv0;
    for (int jj = 0; jj < 5; jj++) {
      unsigned long long key = f5[jj];
      float v = funkey((unsigned)(key >> 32));
      unsigned idx = 0xFFFFFFFFu - (unsigned)(key & 0xFFFFFFFFull);
      lpout[jj] = (v - M) - lse;
      idout[jj] = (float)idx;
    }
    lpout[5] = (sval - M) - lse;
    idout[5] = (float)sidx;
  }
}

extern "C" void kernel_launch(void* const* d_in, const int* in_sizes, int n_in,
                              void* d_out, int out_size, void* d_ws, size_t ws_size,
                              hipStream_t stream) {
  const float* logits = (const float*)d_in[0];
  const float* temp   = (const float*)d_in[1];
  const int*   k      = (const int*)d_in[2];
  const float* p      = (const float*)d_in[3];
  float* out = (float*)d_out;
  const int B = in_sizes[1];
  const int V = in_sizes[0] / in_sizes[1];
  hipLaunchKernelGGL(sampler_kernel, dim3(B), dim3(BLOCK), 0, stream,
                     logits, temp, k, p, out, B, V);
}

// Round 4
// 268.409 us; speedup vs baseline: 1.7180x; 1.7180x over previous
//
#include <hip/hip_runtime.h>
#include <stdint.h>

// PRNG ledger: partitionable threefry, bits = out0 ^ out1 — CONFIRMED exact (round 3, absmax 0).
#define BLOCK 1024
#define NW (BLOCK / 64)
#define CAP 8192

__device__ __forceinline__ unsigned fkey(float x) {
  unsigned u = __float_as_uint(x);
  return (u & 0x80000000u) ? ~u : (u | 0x80000000u);
}
__device__ __forceinline__ float funkey(unsigned k) {
  return __uint_as_float((k & 0x80000000u) ? (k & 0x7FFFFFFFu) : ~k);
}

__device__ __forceinline__ void threefry(unsigned x0, unsigned x1, unsigned& o0, unsigned& o1) {
  const unsigned ks0 = 0u, ks1 = 42u, ks2 = 0u ^ 42u ^ 0x1BD11BDAu;
  x0 += ks0; x1 += ks1;
#define TF_ROUND(r) { x0 += x1; x1 = (x1 << (r)) | (x1 >> (32 - (r))); x1 ^= x0; }
  TF_ROUND(13) TF_ROUND(15) TF_ROUND(26) TF_ROUND(6)
  x0 += ks1; x1 += ks2 + 1u;
  TF_ROUND(17) TF_ROUND(29) TF_ROUND(16) TF_ROUND(24)
  x0 += ks2; x1 += ks0 + 2u;
  TF_ROUND(13) TF_ROUND(15) TF_ROUND(26) TF_ROUND(6)
  x0 += ks0; x1 += ks1 + 3u;
  TF_ROUND(17) TF_ROUND(29) TF_ROUND(16) TF_ROUND(24)
  x0 += ks1; x1 += ks2 + 4u;
  TF_ROUND(13) TF_ROUND(15) TF_ROUND(26) TF_ROUND(6)
  x0 += ks2; x1 += ks0 + 5u;
#undef TF_ROUND
  o0 = x0; o1 = x1;
}

__device__ __forceinline__ float gumbel_from_bits(unsigned bits) {
  const float tiny = 1.17549435e-38f;
  float f = __uint_as_float((bits >> 9) | 0x3F800000u) - 1.0f;
  float u = fmaxf(tiny, f * (1.0f - tiny) + tiny);
  return -logf(-logf(u));
}

__device__ __forceinline__ float gumbel_noise(unsigned long long j) {
  unsigned o0, o1;
  threefry((unsigned)(j >> 32), (unsigned)j, o0, o1);
  return gumbel_from_bits(o0 ^ o1);
}

// Static-index insertion of key into descending t5[0..4] (no runtime-indexed arrays).
#define T5_INSERT(t5, key) do {                                             \
    if ((key) > (t5)[4]) {                                                  \
      (t5)[4] = (key);                                                      \
      unsigned long long _tmp;                                              \
      if ((t5)[4] > (t5)[3]) { _tmp=(t5)[4]; (t5)[4]=(t5)[3]; (t5)[3]=_tmp; }\
      if ((t5)[3] > (t5)[2]) { _tmp=(t5)[3]; (t5)[3]=(t5)[2]; (t5)[2]=_tmp; }\
      if ((t5)[2] > (t5)[1]) { _tmp=(t5)[2]; (t5)[2]=(t5)[1]; (t5)[1]=_tmp; }\
      if ((t5)[1] > (t5)[0]) { _tmp=(t5)[1]; (t5)[1]=(t5)[0]; (t5)[0]=_tmp; }\
    }                                                                       \
  } while (0)

extern "C" __global__ void __launch_bounds__(BLOCK)
sampler_kernel(const float* __restrict__ logits,
               const float* __restrict__ temperature,
               const int* __restrict__ topk,
               const float* __restrict__ topp,
               float* __restrict__ out, int B, int V)
{
  __shared__ unsigned long long cand[CAP];
  __shared__ float aux[CAP];
  __shared__ float redf[NW];
  __shared__ float redf2[NW];
  __shared__ float redf3[NW];
  __shared__ unsigned long long redu[NW];
  __shared__ unsigned long long t5red[NW][5];
  __shared__ int   sh_n0;
  __shared__ float sh_t0, sh_sigma;
  __shared__ int   sh_pos0, sh_pos1;
  __shared__ float sh_S1, sh_S2;
  __shared__ unsigned long long sh_best;

  const int b = blockIdx.x;
  const int tid = threadIdx.x;
  const int lane = tid & 63;
  const int wid = tid >> 6;
  const float t = temperature[b];
  const int kk = topk[b];
  const float p = topp[b];
  const float* __restrict__ row = logits + (size_t)b * V;
  const float4* __restrict__ row4 = (const float4*)row;
  const int N4 = V >> 2;                  // 32000 (V divisible by 4 on bench; tail guard below)
  const float inv = 1.0f / t;             // one exact IEEE divide per row

  // ---- Phase A: sampled stats (16 elems/thread = 16K samples) for threshold guess ----
  {
    float ls = 0.f, ls2 = 0.f;
#pragma unroll
    for (int j = 0; j < 4; j++) {
      int i4 = tid + j * 8192;
      if (i4 < N4) {
        float4 s = row4[i4];
        float a0 = s.x * inv, a1 = s.y * inv, a2 = s.z * inv, a3 = s.w * inv;
        ls += (a0 + a1) + (a2 + a3);
        ls2 += (a0 * a0 + a1 * a1) + (a2 * a2 + a3 * a3);
      }
    }
#pragma unroll
    for (int o = 32; o; o >>= 1) { ls += __shfl_down(ls, o); ls2 += __shfl_down(ls2, o); }
    if (lane == 0) { redf2[wid] = ls; redf3[wid] = ls2; }
    __syncthreads();
    if (tid == 0) {
      float s = 0.f, s2 = 0.f;
      for (int i = 0; i < NW; i++) { s += redf2[i]; s2 += redf3[i]; }
      const float ns = 16384.f;
      float mu = s / ns;
      float var = fmaxf(s2 / ns - mu * mu, 0.f);
      float sigma = sqrtf(var);
      if (!(sigma > 1e-20f)) sigma = 1.f;
      int target = min(4000, max(1344, kk + (kk >> 2) + 192));
      float q = (float)target / (float)V;
      float tt = sqrtf(-2.f * logf(q));
      float z = tt - (2.30753f + 0.27061f * tt) / (1.f + 0.99229f * tt + 0.04481f * tt * tt);
      sh_sigma = sigma;
      sh_t0 = mu + sigma * (z - 0.10f);   // ~1.3x overshoot margin
      sh_n0 = 0;
    }
    __syncthreads();
  }

  // ---- Phase B: single-pass gather + fused exact top-5 tournament ----
  unsigned long long t5[5];
  {
    const unsigned long long kinit = ((unsigned long long)fkey(-INFINITY)) << 32;  // -inf value, idx slot 0
    t5[0] = t5[1] = t5[2] = t5[3] = t5[4] = kinit;
  }
  float t5min = -INFINITY;
  int n0 = 0;
  {
    const float thr = sh_t0;
    for (int i4 = tid; i4 < N4; i4 += BLOCK) {
      float4 xv = row4[i4];
      float x0 = xv.x * inv, x1 = xv.y * inv, x2 = xv.z * inv, x3 = xv.w * inv;
      const int vb = i4 << 2;
      // exact top-5 tournament (value desc, tie -> lowest idx via 0xFFFFFFFF-idx key)
      if (x0 >= t5min) { unsigned long long key = ((unsigned long long)fkey(x0) << 32) | (0xFFFFFFFFu - (unsigned)(vb + 0)); T5_INSERT(t5, key); t5min = funkey((unsigned)(t5[4] >> 32)); }
      if (x1 >= t5min) { unsigned long long key = ((unsigned long long)fkey(x1) << 32) | (0xFFFFFFFFu - (unsigned)(vb + 1)); T5_INSERT(t5, key); t5min = funkey((unsigned)(t5[4] >> 32)); }
      if (x2 >= t5min) { unsigned long long key = ((unsigned long long)fkey(x2) << 32) | (0xFFFFFFFFu - (unsigned)(vb + 2)); T5_INSERT(t5, key); t5min = funkey((unsigned)(t5[4] >> 32)); }
      if (x3 >= t5min) { unsigned long long key = ((unsigned long long)fkey(x3) << 32) | (0xFFFFFFFFu - (unsigned)(vb + 3)); T5_INSERT(t5, key); t5min = funkey((unsigned)(t5[4] >> 32)); }
      bool p0 = (x0 >= thr), p1 = (x1 >= thr), p2 = (x2 >= thr), p3 = (x3 >= thr);
      int cnt = (int)p0 + (int)p1 + (int)p2 + (int)p3;
      if (cnt) {
        int base = atomicAdd(&sh_n0, cnt);
        if (p0 && base < CAP) { cand[base++] = ((unsigned long long)fkey(x0) << 32) | (unsigned)(vb + 0); }
        if (p1 && base < CAP) { cand[base++] = ((unsigned long long)fkey(x1) << 32) | (unsigned)(vb + 1); }
        if (p2 && base < CAP) { cand[base++] = ((unsigned long long)fkey(x2) << 32) | (unsigned)(vb + 2); }
        if (p3 && base < CAP) { cand[base++] = ((unsigned long long)fkey(x3) << 32) | (unsigned)(vb + 3); }
      }
    }
    __syncthreads();
    n0 = sh_n0;
  }

  // ---- Retry loop (never taken on bench input; guarantees correctness) ----
  for (int attempt = 1; attempt < 8 && (n0 < kk || n0 > CAP); ++attempt) {
    if (tid == 0) {
      if (n0 < kk) sh_t0 -= 0.5f * sh_sigma;
      else         sh_t0 += 0.25f * sh_sigma;
      sh_n0 = 0;
    }
    __syncthreads();
    const float thr = sh_t0;
    for (int i4 = tid; i4 < N4; i4 += BLOCK) {
      float4 xv = row4[i4];
      float x0 = xv.x * inv, x1 = xv.y * inv, x2 = xv.z * inv, x3 = xv.w * inv;
      const int vb = i4 << 2;
      bool p0 = (x0 >= thr), p1 = (x1 >= thr), p2 = (x2 >= thr), p3 = (x3 >= thr);
      int cnt = (int)p0 + (int)p1 + (int)p2 + (int)p3;
      if (cnt) {
        int base = atomicAdd(&sh_n0, cnt);
        if (p0 && base < CAP) { cand[base++] = ((unsigned long long)fkey(x0) << 32) | (unsigned)(vb + 0); }
        if (p1 && base < CAP) { cand[base++] = ((unsigned long long)fkey(x1) << 32) | (unsigned)(vb + 1); }
        if (p2 && base < CAP) { cand[base++] = ((unsigned long long)fkey(x2) << 32) | (unsigned)(vb + 2); }
        if (p3 && base < CAP) { cand[base++] = ((unsigned long long)fkey(x3) << 32) | (unsigned)(vb + 3); }
      }
    }
    __syncthreads();
    n0 = sh_n0;
  }
  if (n0 > CAP) n0 = CAP;

  // ---- Tournament reduction: wave merge via shfl, then to LDS ----
  {
#pragma unroll
    for (int off = 32; off; off >>= 1) {
      unsigned long long o0 = __shfl_down(t5[0], off);
      unsigned long long o1 = __shfl_down(t5[1], off);
      unsigned long long o2 = __shfl_down(t5[2], off);
      unsigned long long o3 = __shfl_down(t5[3], off);
      unsigned long long o4 = __shfl_down(t5[4], off);
      T5_INSERT(t5, o0); T5_INSERT(t5, o1); T5_INSERT(t5, o2);
      T5_INSERT(t5, o3); T5_INSERT(t5, o4);
    }
    if (lane == 0) {
      t5red[wid][0] = t5[0]; t5red[wid][1] = t5[1]; t5red[wid][2] = t5[2];
      t5red[wid][3] = t5[3]; t5red[wid][4] = t5[4];
    }
  }
  __syncthreads();

  if (n0 < 1) {
    if (tid == 0) {
      out[b] = 0.f;
      for (int j = 0; j < 6; j++) { out[B + b * 6 + j] = 0.f; out[B + B * 6 + b * 6 + j] = 0.f; }
    }
    return;
  }

  // ---- Phase C: bitonic sort ascending by (value_key, idx) ----
  int n = 1; while (n < n0) n <<= 1;
  if (n < 2) n = 2;
  for (int i = n0 + tid; i < n; i += BLOCK) cand[i] = 0xFFFFFFFFFFFFFFFFull;
  __syncthreads();
  for (int sz = 2; sz <= n; sz <<= 1) {
    for (int st = sz >> 1; st > 0; st >>= 1) {
      for (int i = tid; i < n; i += BLOCK) {
        int j = i ^ st;
        if (j > i) {
          unsigned long long a = cand[i], c = cand[j];
          bool up = ((i & sz) == 0);
          if ((a > c) == up) { cand[i] = c; cand[j] = a; }
        }
      }
      __syncthreads();
    }
  }

  const float M = funkey((unsigned)(cand[n0 - 1] >> 32));   // exact row max

  // ---- Phase D: top-k threshold position (ties kept) ----
  if (tid == 0) {
    int kc = min(kk, n0);
    unsigned tk = (unsigned)(cand[n0 - kc] >> 32);
    int lo = 0, hi = n0 - kc;
    while (lo < hi) { int mid = (lo + hi) >> 1;
      if ((unsigned)(cand[mid] >> 32) >= tk) hi = mid; else lo = mid + 1; }
    sh_pos0 = lo;
  }
  __syncthreads();
  const int pos0 = sh_pos0;

  // ---- q_i = exp(x - M) for kept-by-topk; S1 = sum ----
  for (int i = tid; i < n0; i += BLOCK) {
    float v = funkey((unsigned)(cand[i] >> 32));
    aux[i] = (i >= pos0) ? expf(v - M) : 0.f;
  }
  __syncthreads();
  {
    float sloc = 0.f;
    for (int i = tid; i < n0; i += BLOCK) sloc += aux[i];
#pragma unroll
    for (int o = 32; o; o >>= 1) sloc += __shfl_down(sloc, o);
    if (lane == 0) redf[wid] = sloc;
    __syncthreads();
    if (tid == 0) { float s = 0.f; for (int i = 0; i < NW; i++) s += redf[i]; sh_S1 = s; }
    __syncthreads();
  }
  const float S1 = sh_S1;

  // ---- inclusive cumsum of p_i = q_i/S1 (chunked + shfl scan, 3 barriers) ----
  const int C = (n0 + BLOCK - 1) / BLOCK;
  const int beg = tid * C, endp = min(beg + C, n0);
  float sp = 0.f;
  for (int i = beg; i < endp; i++) sp += aux[i] / S1;
  float ws = sp;
#pragma unroll
  for (int off = 1; off < 64; off <<= 1) {
    float v = __shfl_up(ws, off);
    if (lane >= off) ws += v;
  }
  if (lane == 63) redf[wid] = ws;
  __syncthreads();
  if (tid < NW) {
    float v = redf[tid];
#pragma unroll
    for (int off = 1; off < NW; off <<= 1) {
      float u = __shfl_up(v, off);
      if (tid >= off) v += u;
    }
    redf[tid] = v;
  }
  __syncthreads();
  {
    float wbase = (wid > 0) ? redf[wid - 1] : 0.f;
    float run = wbase + (ws - sp);          // exclusive prefix for this thread's chunk
    for (int i = beg; i < endp; i++) { run += aux[i] / S1; aux[i] = run; }
  }
  __syncthreads();

  // ---- top-p cut: first pos with cum > 1-p ----
  const float cutoff = 1.0f - p;
  if (tid == 0) {
    int lo = pos0, hi = n0 - 1;
    while (lo < hi) { int mid = (lo + hi) >> 1;
      if (aux[mid] > cutoff) hi = mid; else lo = mid + 1; }
    sh_pos1 = lo;
  }
  __syncthreads();
  const int pos1 = sh_pos1;

  // ---- S2 over final kept set ----
  {
    float sloc = 0.f;
    for (int i = pos1 + tid; i < n0; i += BLOCK) {
      float v = funkey((unsigned)(cand[i] >> 32));
      sloc += expf(v - M);
    }
#pragma unroll
    for (int o = 32; o; o >>= 1) sloc += __shfl_down(sloc, o);
    if (lane == 0) redf2[wid] = sloc;
    __syncthreads();
    if (tid == 0) { float s = 0.f; for (int i = 0; i < NW; i++) s += redf2[i]; sh_S2 = s; }
    __syncthreads();
  }

  // ---- Gumbel-max sampling (exact JAX threefry; first-occurrence tie-break) ----
  unsigned long long best = 0ull;
  for (int i = pos1 + tid; i < n0; i += BLOCK) {
    unsigned idx = (unsigned)(cand[i] & 0xFFFFFFFFull);
    unsigned long long j = (unsigned long long)b * (unsigned long long)V + idx;
    float g = gumbel_noise(j);
    float v = funkey((unsigned)(cand[i] >> 32));
    float sc = v + g;
    unsigned long long pk =
        ((unsigned long long)fkey(sc) << 32) | (unsigned)(0xFFFFFFFFu - (unsigned)i);
    if (pk > best) best = pk;
  }
#pragma unroll
  for (int o = 32; o; o >>= 1) {
    unsigned long long o2 = __shfl_down(best, o);
    if (o2 > best) best = o2;
  }
  if (lane == 0) redu[wid] = best;
  __syncthreads();
  if (tid == 0) {
    unsigned long long bb = 0ull;
    for (int i = 0; i < NW; i++) if (redu[i] > bb) bb = redu[i];
    sh_best = bb;
  }
  __syncthreads();

  // ---- Phase E: outputs ----
  if (tid == 0) {
    const float lse = logf(sh_S2);
    int bi = (int)(0xFFFFFFFFu - (unsigned)(sh_best & 0xFFFFFFFFull));
    unsigned sidx = (unsigned)(cand[bi] & 0xFFFFFFFFull);
    float sval = funkey((unsigned)(cand[bi] >> 32));

    unsigned long long f5[5] = {0ull, 0ull, 0ull, 0ull, 0ull};
    for (int w = 0; w < NW; w++) {
      unsigned long long k0 = t5red[w][0], k1 = t5red[w][1], k2 = t5red[w][2],
                         k3 = t5red[w][3], k4 = t5red[w][4];
      T5_INSERT(f5, k0); T5_INSERT(f5, k1); T5_INSERT(f5, k2);
      T5_INSERT(f5, k3); T5_INSERT(f5, k4);
    }

    out[b] = (float)sidx;
    float* lpout = out + B + b * 6;
    float* idout = out + B + B * 6 + b * 6;
    for (int jj = 0; jj < 5; jj++) {
      unsigned long long key = f5[jj];
      float v = funkey((unsigned)(key >> 32));
      unsigned idx = 0xFFFFFFFFu - (unsigned)(key & 0xFFFFFFFFull);
      lpout[jj] = (v - M) - lse;
      idout[jj] = (float)idx;
    }
    lpout[5] = (sval - M) - lse;
    idout[5] = (float)sidx;
  }
}

extern "C" void kernel_launch(void* const* d_in, const int* in_sizes, int n_in,
                              void* d_out, int out_size, void* d_ws, size_t ws_size,
                              hipStream_t stream) {
  const float* logits = (const float*)d_in[0];
  const float* temp   = (const float*)d_in[1];
  const int*   k      = (const int*)d_in[2];
  const float* p      = (const float*)d_in[3];
  float* out = (float*)d_out;
  const int B = in_sizes[1];
  const int V = in_sizes[0] / in_sizes[1];
  hipLaunchKernelGGL(sampler_kernel, dim3(B), dim3(BLOCK), 0, stream,
                     logits, temp, k, p, out, B, V);
}

// Round 5
// 247.493 us; speedup vs baseline: 1.8632x; 1.0845x over previous
//
#include <hip/hip_runtime.h>
#include <stdint.h>

// PRNG ledger: partitionable threefry, bits = out0 ^ out1 — CONFIRMED exact (rounds 3/4, absmax 0).
#define BLOCK 1024
#define NW (BLOCK / 64)
#define CAP 4096

__device__ __forceinline__ unsigned fkey(float x) {
  unsigned u = __float_as_uint(x);
  return (u & 0x80000000u) ? ~u : (u | 0x80000000u);
}
__device__ __forceinline__ float funkey(unsigned k) {
  return __uint_as_float((k & 0x80000000u) ? (k & 0x7FFFFFFFu) : ~k);
}

__device__ __forceinline__ void threefry(unsigned x0, unsigned x1, unsigned& o0, unsigned& o1) {
  const unsigned ks0 = 0u, ks1 = 42u, ks2 = 0u ^ 42u ^ 0x1BD11BDAu;
  x0 += ks0; x1 += ks1;
#define TF_ROUND(r) { x0 += x1; x1 = (x1 << (r)) | (x1 >> (32 - (r))); x1 ^= x0; }
  TF_ROUND(13) TF_ROUND(15) TF_ROUND(26) TF_ROUND(6)
  x0 += ks1; x1 += ks2 + 1u;
  TF_ROUND(17) TF_ROUND(29) TF_ROUND(16) TF_ROUND(24)
  x0 += ks2; x1 += ks0 + 2u;
  TF_ROUND(13) TF_ROUND(15) TF_ROUND(26) TF_ROUND(6)
  x0 += ks0; x1 += ks1 + 3u;
  TF_ROUND(17) TF_ROUND(29) TF_ROUND(16) TF_ROUND(24)
  x0 += ks1; x1 += ks2 + 4u;
  TF_ROUND(13) TF_ROUND(15) TF_ROUND(26) TF_ROUND(6)
  x0 += ks2; x1 += ks0 + 5u;
#undef TF_ROUND
  o0 = x0; o1 = x1;
}

__device__ __forceinline__ float gumbel_from_bits(unsigned bits) {
  const float tiny = 1.17549435e-38f;
  float f = __uint_as_float((bits >> 9) | 0x3F800000u) - 1.0f;
  float u = fmaxf(tiny, f * (1.0f - tiny) + tiny);
  return -logf(-logf(u));
}

__device__ __forceinline__ float gumbel_noise(unsigned long long j) {
  unsigned o0, o1;
  threefry((unsigned)(j >> 32), (unsigned)j, o0, o1);
  return gumbel_from_bits(o0 ^ o1);
}

// Static-index insertion of key into descending t5[0..4] (no runtime-indexed arrays).
#define T5_INSERT(t5, key) do {                                             \
    if ((key) > (t5)[4]) {                                                  \
      (t5)[4] = (key);                                                      \
      unsigned long long _tmp;                                              \
      if ((t5)[4] > (t5)[3]) { _tmp=(t5)[4]; (t5)[4]=(t5)[3]; (t5)[3]=_tmp; }\
      if ((t5)[3] > (t5)[2]) { _tmp=(t5)[3]; (t5)[3]=(t5)[2]; (t5)[2]=_tmp; }\
      if ((t5)[2] > (t5)[1]) { _tmp=(t5)[2]; (t5)[2]=(t5)[1]; (t5)[1]=_tmp; }\
      if ((t5)[1] > (t5)[0]) { _tmp=(t5)[1]; (t5)[1]=(t5)[0]; (t5)[0]=_tmp; }\
    }                                                                       \
  } while (0)

extern "C" __global__ void __launch_bounds__(BLOCK)
sampler_kernel(const float* __restrict__ logits,
               const float* __restrict__ temperature,
               const int* __restrict__ topk,
               const float* __restrict__ topp,
               float* __restrict__ out, int B, int V)
{
  __shared__ unsigned long long cand[CAP];
  __shared__ float aux[CAP];
  __shared__ float redf[NW];
  __shared__ float redf2[NW];
  __shared__ float redf3[NW];
  __shared__ unsigned long long redu[NW];
  __shared__ unsigned long long t5red[NW][5];
  __shared__ int   sh_n0;
  __shared__ float sh_t0, sh_sigma;
  __shared__ int   sh_pos0, sh_pos1;
  __shared__ float sh_S1, sh_S2;
  __shared__ unsigned long long sh_best;

  const int b = blockIdx.x;
  const int tid = threadIdx.x;
  const int lane = tid & 63;
  const int wid = tid >> 6;
  const float t = temperature[b];
  const int kk = topk[b];
  const float p = topp[b];
  const float* __restrict__ row = logits + (size_t)b * V;
  const float4* __restrict__ row4 = (const float4*)row;
  const int N4 = V >> 2;
  const float inv = 1.0f / t;   // one exact divide per row; t > 0 so raw order == scaled order

  // ---- Phase A: RAW-domain subsample stats (16K samples) -> threshold guess ----
  {
    float ls = 0.f, ls2 = 0.f;
#pragma unroll
    for (int j = 0; j < 4; j++) {
      int i4 = tid + j * 8192;
      if (i4 < N4) {
        float4 s = row4[i4];
        ls  += (s.x + s.y) + (s.z + s.w);
        ls2 += (s.x * s.x + s.y * s.y) + (s.z * s.z + s.w * s.w);
      }
    }
#pragma unroll
    for (int o = 32; o; o >>= 1) { ls += __shfl_down(ls, o); ls2 += __shfl_down(ls2, o); }
    if (lane == 0) { redf2[wid] = ls; redf3[wid] = ls2; }
    __syncthreads();
    if (tid == 0) {
      float s = 0.f, s2 = 0.f;
      for (int i = 0; i < NW; i++) { s += redf2[i]; s2 += redf3[i]; }
      const float ns = 16384.f;
      float mu = s / ns;
      float var = fmaxf(s2 / ns - mu * mu, 0.f);
      float sigma = sqrtf(var);
      if (!(sigma > 1e-20f)) sigma = 1.f;
      int target = min(2800, max(kk + (kk >> 2) + 128, 512));
      float q = (float)target / (float)V;
      float tt = sqrtf(-2.f * logf(q));
      float z = tt - (2.30753f + 0.27061f * tt) / (1.f + 0.99229f * tt + 0.04481f * tt * tt);
      sh_sigma = sigma;
      sh_t0 = mu + sigma * (z - 0.10f);
      sh_n0 = 0;
    }
    __syncthreads();
  }

  // ---- Phase B: single-pass gather, RAW-domain predicate, 2-deep load unroll,
  //      wave-scan compaction (1 atomic per wave-iter). Scaled key only for passers. ----
  int n0 = 0;
  {
    const float thr = sh_t0;
    for (int i4 = tid; i4 < N4; i4 += 2 * BLOCK) {
      float4 A = row4[i4];
      int ib = i4 + BLOCK;
      bool hb = (ib < N4);
      if (!hb) ib = i4;
      float4 Bv = row4[ib];
      bool a0 = A.x >= thr, a1 = A.y >= thr, a2 = A.z >= thr, a3 = A.w >= thr;
      bool b0 = hb && (Bv.x >= thr), b1 = hb && (Bv.y >= thr),
           b2 = hb && (Bv.z >= thr), b3 = hb && (Bv.w >= thr);
      int cnt = (int)a0 + (int)a1 + (int)a2 + (int)a3
              + (int)b0 + (int)b1 + (int)b2 + (int)b3;
      int incl = cnt;
#pragma unroll
      for (int off = 1; off < 64; off <<= 1) {
        int v = __shfl_up(incl, off);
        if (lane >= off) incl += v;
      }
      int tot = __shfl(incl, 63);
      if (tot) {
        int base = 0;
        if (lane == 63) base = atomicAdd(&sh_n0, tot);
        base = __shfl(base, 63);
        int mb = base + incl - cnt;
        const int va = i4 << 2, vb = ib << 2;
        if (a0) { if (mb < CAP) cand[mb] = ((unsigned long long)fkey(A.x * inv) << 32) | (unsigned)(va + 0); mb++; }
        if (a1) { if (mb < CAP) cand[mb] = ((unsigned long long)fkey(A.y * inv) << 32) | (unsigned)(va + 1); mb++; }
        if (a2) { if (mb < CAP) cand[mb] = ((unsigned long long)fkey(A.z * inv) << 32) | (unsigned)(va + 2); mb++; }
        if (a3) { if (mb < CAP) cand[mb] = ((unsigned long long)fkey(A.w * inv) << 32) | (unsigned)(va + 3); mb++; }
        if (b0) { if (mb < CAP) cand[mb] = ((unsigned long long)fkey(Bv.x * inv) << 32) | (unsigned)(vb + 0); mb++; }
        if (b1) { if (mb < CAP) cand[mb] = ((unsigned long long)fkey(Bv.y * inv) << 32) | (unsigned)(vb + 1); mb++; }
        if (b2) { if (mb < CAP) cand[mb] = ((unsigned long long)fkey(Bv.z * inv) << 32) | (unsigned)(vb + 2); mb++; }
        if (b3) { if (mb < CAP) cand[mb] = ((unsigned long long)fkey(Bv.w * inv) << 32) | (unsigned)(vb + 3); mb++; }
      }
    }
    __syncthreads();
    n0 = sh_n0;
  }

  // ---- Retry loop (never taken on bench input; correctness guarantee) ----
  for (int attempt = 1; attempt < 8 && (n0 < kk || n0 > CAP); ++attempt) {
    if (tid == 0) {
      if (n0 < kk) sh_t0 -= 0.5f * sh_sigma;
      else         sh_t0 += 0.25f * sh_sigma;
      sh_n0 = 0;
    }
    __syncthreads();
    const float thr = sh_t0;
    for (int i4 = tid; i4 < N4; i4 += BLOCK) {
      float4 xv = row4[i4];
      bool p0 = xv.x >= thr, p1 = xv.y >= thr, p2 = xv.z >= thr, p3 = xv.w >= thr;
      int cnt = (int)p0 + (int)p1 + (int)p2 + (int)p3;
      if (cnt) {
        int base = atomicAdd(&sh_n0, cnt);
        const int vbb = i4 << 2;
        if (p0) { if (base < CAP) cand[base] = ((unsigned long long)fkey(xv.x * inv) << 32) | (unsigned)(vbb + 0); base++; }
        if (p1) { if (base < CAP) cand[base] = ((unsigned long long)fkey(xv.y * inv) << 32) | (unsigned)(vbb + 1); base++; }
        if (p2) { if (base < CAP) cand[base] = ((unsigned long long)fkey(xv.z * inv) << 32) | (unsigned)(vbb + 2); base++; }
        if (p3) { if (base < CAP) cand[base] = ((unsigned long long)fkey(xv.w * inv) << 32) | (unsigned)(vbb + 3); base++; }
      }
    }
    __syncthreads();
    n0 = sh_n0;
  }
  if (n0 > CAP) n0 = CAP;

  if (n0 < 1) {
    if (tid == 0) {
      out[b] = 0.f;
      for (int j = 0; j < 6; j++) { out[B + b * 6 + j] = 0.f; out[B + B * 6 + b * 6 + j] = 0.f; }
    }
    return;
  }

  // ---- Phase C: bitonic sort ascending by (scaled_key, idx) ----
  int n = 1; while (n < n0) n <<= 1;
  if (n < 2) n = 2;
  for (int i = n0 + tid; i < n; i += BLOCK) cand[i] = 0xFFFFFFFFFFFFFFFFull;
  __syncthreads();
  for (int sz = 2; sz <= n; sz <<= 1) {
    for (int st = sz >> 1; st > 0; st >>= 1) {
      for (int i = tid; i < n; i += BLOCK) {
        int j = i ^ st;
        if (j > i) {
          unsigned long long a = cand[i], c = cand[j];
          bool up = ((i & sz) == 0);
          if ((a > c) == up) { cand[i] = c; cand[j] = a; }
        }
      }
      __syncthreads();
    }
  }

  const float M = funkey((unsigned)(cand[n0 - 1] >> 32));   // exact row max

  // ---- Exact top-5 tournament over the candidate set (order-independent, proven) ----
  {
    unsigned long long t5[5] = {0ull, 0ull, 0ull, 0ull, 0ull};
    for (int i = tid; i < n0; i += BLOCK) {
      unsigned long long ck = cand[i];
      unsigned long long tk = (ck & 0xFFFFFFFF00000000ull) |
                              (unsigned)(0xFFFFFFFFu - (unsigned)(ck & 0xFFFFFFFFull));
      T5_INSERT(t5, tk);
    }
#pragma unroll
    for (int off = 32; off; off >>= 1) {
      unsigned long long o0 = __shfl_down(t5[0], off);
      unsigned long long o1 = __shfl_down(t5[1], off);
      unsigned long long o2 = __shfl_down(t5[2], off);
      unsigned long long o3 = __shfl_down(t5[3], off);
      unsigned long long o4 = __shfl_down(t5[4], off);
      T5_INSERT(t5, o0); T5_INSERT(t5, o1); T5_INSERT(t5, o2);
      T5_INSERT(t5, o3); T5_INSERT(t5, o4);
    }
    if (lane == 0) {
      t5red[wid][0] = t5[0]; t5red[wid][1] = t5[1]; t5red[wid][2] = t5[2];
      t5red[wid][3] = t5[3]; t5red[wid][4] = t5[4];
    }
  }

  // ---- Phase D: top-k threshold position (ties kept) ----
  if (tid == 0) {
    int kc = min(kk, n0);
    unsigned tk = (unsigned)(cand[n0 - kc] >> 32);
    int lo = 0, hi = n0 - kc;
    while (lo < hi) { int mid = (lo + hi) >> 1;
      if ((unsigned)(cand[mid] >> 32) >= tk) hi = mid; else lo = mid + 1; }
    sh_pos0 = lo;
  }
  __syncthreads();
  const int pos0 = sh_pos0;

  // ---- q_i = exp(x - M) on [pos0, n0); S1 = sum ----
  for (int i = pos0 + tid; i < n0; i += BLOCK) {
    float v = funkey((unsigned)(cand[i] >> 32));
    aux[i] = expf(v - M);
  }
  __syncthreads();
  {
    float sloc = 0.f;
    for (int i = pos0 + tid; i < n0; i += BLOCK) sloc += aux[i];
#pragma unroll
    for (int o = 32; o; o >>= 1) sloc += __shfl_down(sloc, o);
    if (lane == 0) redf[wid] = sloc;
    __syncthreads();
    if (tid == 0) { float s = 0.f; for (int i = 0; i < NW; i++) s += redf[i]; sh_S1 = s; }
    __syncthreads();
  }
  const float S1 = sh_S1;

  // ---- inclusive cumsum of p_i = q_i/S1 on [pos0, n0) (chunked + shfl scan) ----
  const int m = n0 - pos0;
  const int C = (m + BLOCK - 1) / BLOCK;
  const int beg = pos0 + tid * C;
  const int endp = min(beg + C, n0);
  float sp = 0.f;
  for (int i = beg; i < endp; i++) sp += aux[i] / S1;
  float ws = sp;
#pragma unroll
  for (int off = 1; off < 64; off <<= 1) {
    float v = __shfl_up(ws, off);
    if (lane >= off) ws += v;
  }
  if (lane == 63) redf[wid] = ws;
  __syncthreads();
  if (tid < NW) {
    float v = redf[tid];
#pragma unroll
    for (int off = 1; off < NW; off <<= 1) {
      float u = __shfl_up(v, off);
      if (tid >= off) v += u;
    }
    redf[tid] = v;
  }
  __syncthreads();
  {
    float wbase = (wid > 0) ? redf[wid - 1] : 0.f;
    float run = wbase + (ws - sp);
    for (int i = beg; i < endp; i++) { run += aux[i] / S1; aux[i] = run; }
  }
  __syncthreads();

  // ---- top-p cut: first pos in [pos0, n0) with cum > 1-p ----
  const float cutoff = 1.0f - p;
  if (tid == 0) {
    int lo = pos0, hi = n0 - 1;
    while (lo < hi) { int mid = (lo + hi) >> 1;
      if (aux[mid] > cutoff) hi = mid; else lo = mid + 1; }
    sh_pos1 = lo;
  }
  __syncthreads();
  const int pos1 = sh_pos1;

  // ---- S2 over final kept set [pos1, n0) ----
  {
    float sloc = 0.f;
    for (int i = pos1 + tid; i < n0; i += BLOCK) {
      float v = funkey((unsigned)(cand[i] >> 32));
      sloc += expf(v - M);
    }
#pragma unroll
    for (int o = 32; o; o >>= 1) sloc += __shfl_down(sloc, o);
    if (lane == 0) redf2[wid] = sloc;
    __syncthreads();
    if (tid == 0) { float s = 0.f; for (int i = 0; i < NW; i++) s += redf2[i]; sh_S2 = s; }
    __syncthreads();
  }

  // ---- Gumbel-max sampling over [pos1, n0) (exact JAX threefry) ----
  unsigned long long best = 0ull;
  for (int i = pos1 + tid; i < n0; i += BLOCK) {
    unsigned idx = (unsigned)(cand[i] & 0xFFFFFFFFull);
    unsigned long long j = (unsigned long long)b * (unsigned long long)V + idx;
    float g = gumbel_noise(j);
    float v = funkey((unsigned)(cand[i] >> 32));
    float sc = v + g;
    unsigned long long pk =
        ((unsigned long long)fkey(sc) << 32) | (unsigned)(0xFFFFFFFFu - (unsigned)i);
    if (pk > best) best = pk;
  }
#pragma unroll
  for (int o = 32; o; o >>= 1) {
    unsigned long long o2 = __shfl_down(best, o);
    if (o2 > best) best = o2;
  }
  if (lane == 0) redu[wid] = best;
  __syncthreads();
  if (tid == 0) {
    unsigned long long bb = 0ull;
    for (int i = 0; i < NW; i++) if (redu[i] > bb) bb = redu[i];
    sh_best = bb;
  }
  __syncthreads();

  // ---- Phase E: outputs ----
  if (tid == 0) {
    const float lse = logf(sh_S2);
    int bi = (int)(0xFFFFFFFFu - (unsigned)(sh_best & 0xFFFFFFFFull));
    unsigned sidx = (unsigned)(cand[bi] & 0xFFFFFFFFull);
    float sval = funkey((unsigned)(cand[bi] >> 32));

    unsigned long long f5[5] = {0ull, 0ull, 0ull, 0ull, 0ull};
    for (int w = 0; w < NW; w++) {
      unsigned long long k0 = t5red[w][0], k1 = t5red[w][1], k2 = t5red[w][2],
                         k3 = t5red[w][3], k4 = t5red[w][4];
      T5_INSERT(f5, k0); T5_INSERT(f5, k1); T5_INSERT(f5, k2);
      T5_INSERT(f5, k3); T5_INSERT(f5, k4);
    }

    out[b] = (float)sidx;
    float* lpout = out + B + b * 6;
    float* idout = out + B + B * 6 + b * 6;
    for (int jj = 0; jj < 5; jj++) {
      unsigned long long key = f5[jj];
      float v = funkey((unsigned)(key >> 32));
      unsigned idx = 0xFFFFFFFFu - (unsigned)(key & 0xFFFFFFFFull);
      lpout[jj] = (v - M) - lse;
      idout[jj] = (float)idx;
    }
    lpout[5] = (sval - M) - lse;
    idout[5] = (float)sidx;
  }
}

extern "C" void kernel_launch(void* const* d_in, const int* in_sizes, int n_in,
                              void* d_out, int out_size, void* d_ws, size_t ws_size,
                              hipStream_t stream) {
  const float* logits = (const float*)d_in[0];
  const float* temp   = (const float*)d_in[1];
  const int*   k      = (const int*)d_in[2];
  const float* p      = (const float*)d_in[3];
  float* out = (float*)d_out;
  const int B = in_sizes[1];
  const int V = in_sizes[0] / in_sizes[1];
  hipLaunchKernelGGL(sampler_kernel, dim3(B), dim3(BLOCK), 0, stream,
                     logits, temp, k, p, out, B, V);
}